// Round 16
// baseline (261.239 us; speedup 1.0000x reference)
//
#include <hip/hip_runtime.h>
#include <hip/hip_bf16.h>

// Net_22625887715641: fused conv-feats + channel-normalize + 32x32 normalized
// cross-correlation (23x23 shifts, 362x362 templates).
//
// R26 vs R25 (total 259.9; feat occupancy-insensitive -> not latency-bound):
//  feat (~125us of the 134us non-corr tail) runs at ~4x its additive floor
//  (~30us VALU + ~20us LDS) with waves issuing ~25% of slots, INDEPENDENT
//  of occupancy (R25 A/B). Two occupancy-independent suspects:
//  (1) forced spill: launch_bounds(128,4) caps VGPR at 128; in-loop live
//      set ~95-130 is at the cap (R16 lesson: spill = silent 4-5x).
//  (2) per-iteration ILP starvation: rolled a-loop = {loads -> waitcnt ->
//      176-352 FMA} serial per iteration.
//  R26 = R25 + two one-line feat changes targeting both:
//  - launch_bounds (128,4) -> (128,2): VGPR cap 256, no forced spill.
//    (R25 proved the traded occupancy was worthless.)
//  - #pragma unroll 2 on the a-loop: two independent iterations in flight;
//    intra-wave ILP hides load latency without co-resident waves.
//  corr / prep byte-identical (corr plateau: R17/R18/R20/R23 all 124-128).

typedef unsigned short ushort_t;
typedef unsigned int uint_t;
typedef unsigned char uchar_t;
typedef __attribute__((ext_vector_type(4))) float f32x4;
typedef __attribute__((ext_vector_type(16))) float f32x16;
typedef __attribute__((ext_vector_type(4))) uint_t uint4_t;
typedef __attribute__((ext_vector_type(2))) uint_t uint2_t;
typedef __attribute__((ext_vector_type(8))) int int8v;

#define EPSF 2.2204460492503131e-16f
#define X1_N (32*384*384)
#define X2_N (32*32*23*23)

// filtb: fp8 [372 rows][kt64 6][h 2][kg 2][o 32][16B]; row = yf+5
#define FILTB_ROW_B 12288
#define FILTB_BYTES (372*48*32*8)
// prevb: fp8 [32 c][385 rows][432 x]; data rows 0..383 cols 0..383; zeros else
#define PREVB_STRIDE 432
#define PREVB_BYTES (32*385*PREVB_STRIDE)
#define ZERO_BYTES ((size_t)FILTB_BYTES + PREVB_BYTES)
// fT2: fp32 [16 chp][45 rows][12] after prevb
#define FT2_ELEMS (16*45*12)

// prep fused-zero ranges (16B units)
#define ZERO16 (ZERO_BYTES / 16)            // 618,336
#define X2Z16  ((X2_N * 4) / 16)            // 135,424
#define PREP_WORK (ZERO16 + X2Z16 + FT2_ELEMS)

#define YMAX 367            // y-steps 0..366
#define NCHUNKS 16          // 16 chpairs x 16 chunks = 256 blocks = 1/CU
#define INV_AREA (1.0f/131044.0f)

// One prev y-row image in LDS: [dyb 4][copy 8][432]; copy stride 432
#define SB_COPY_B 432
#define SB_DYB_B  (8*SB_COPY_B)     // 3456
#define SB_ROW_B  (4*SB_DYB_B)      // 13824 B per y-row image
#define SB_BYTES  (2*2*SB_ROW_B)    // [group][buf] = 55296 B

// A-ring: 8 slots x one filtb row
#define SA_BYTES  (8*FILTB_ROW_B)   // 98304 B
#define SMEM_TOTAL (SA_BYTES + SB_BYTES)   // 153600 B

// ---------------------------------------------------------------------------
// fp32 -> fp8 e4m3 (OCP), RNE, input assumed in [0, 448).
// ---------------------------------------------------------------------------
__device__ __forceinline__ uint_t f32_to_e4m3(float f) {
  if (f < 0.015625f)                         // subnormal: m * 2^-9
    return (uint_t)__float2int_rn(f * 512.0f);
  uint_t b = __builtin_bit_cast(uint_t, f);
  int e = (int)(b >> 23) - 127;
  uint_t m = b & 0x7FFFFFu;
  uint_t keep = m >> 20;
  uint_t rest = m & 0xFFFFFu;
  keep += (rest > 0x80000u) || (rest == 0x80000u && (keep & 1u));
  if (keep == 8u) { keep = 0u; e += 1; }
  if (e > 8) return 0x7Eu;                   // saturate 448
  return (uint_t)(((e + 7) << 3) | keep);
}

// ---------------------------------------------------------------------------
// Prep (fused): zero filtb+prevb, zero x2, pack filters to fT2.
// ---------------------------------------------------------------------------
__global__ void prep_kernel(const float* __restrict__ ft, const float* __restrict__ fn,
                            float* __restrict__ fT2, uchar_t* __restrict__ wsz,
                            float* __restrict__ x2)
{
  const long e = (long)blockIdx.x * 256 + threadIdx.x;
  if (e < (long)ZERO16) {
    ((uint4_t*)wsz)[e] = uint4_t{0u, 0u, 0u, 0u};
  } else if (e < (long)(ZERO16 + X2Z16)) {
    ((uint4_t*)x2)[e - ZERO16] = uint4_t{0u, 0u, 0u, 0u};
  } else if (e < (long)PREP_WORK) {
    const int e2 = (int)(e - ZERO16 - X2Z16);
    const int chp = e2 / 540;
    const int rem = e2 - chp * 540;
    const int row = rem / 12;
    const int j = rem - row * 12;
    float v = 0.f;
    if (j < 11) {
      if (row < 33)      v = ft[chp * 363 + row * 11 + j];        // row = t*11+a
      else if (row < 44) v = fn[chp * 121 + (row - 33) * 11 + j]; // row-33 = a
    }
    fT2[e2] = v;
  }
}

// ---------------------------------------------------------------------------
// Stage 1: thread = (ch-pair chp) x (16-px row). Block 128 = 8 rows x 16 chp.
// mode 0: x -> x1 (fp32 direct stores) AND direct fp8 byte-pack into filtb.
// mode 1: xprev -> prevb (fp8 e4m3).
// launch_bounds (128,2): VGPR cap 256 (no forced spill); a-loop unroll 2
// for intra-wave ILP across iterations.
// ---------------------------------------------------------------------------
__global__ __launch_bounds__(128, 2) void feat_kernel(
    const float* __restrict__ xcur, const float* __restrict__ xprev,
    const float* __restrict__ fT2,
    float* __restrict__ out_x1, uchar_t* __restrict__ prevb,
    uchar_t* __restrict__ filtb)
{
  __shared__ float sPx[3 * 18 * 28];
  const int tid = threadIdx.x;
  const int chp = tid & 15;
  const int r = tid >> 4;              // 0..7
  const int j0 = blockIdx.x * 16;
  const int i0 = blockIdx.y * 8;
  const int i = i0 + r;
  const int mode = blockIdx.z;
  const float* __restrict__ xin = mode ? xprev : xcur;

  for (int e = tid; e < 3 * 18 * 26; e += 128) {
    const int t = e / 468;
    const int rem = e - t * 468;
    const int ri = rem / 26;
    const int ci = rem - ri * 26;
    sPx[(t * 18 + ri) * 28 + ci] = xin[((size_t)t * 394 + i0 + ri) * 394 + j0 + ci];
  }
  __syncthreads();

  const float* __restrict__ fbase = fT2 + chp * 540;

  float accT[16], accN[16];
#pragma unroll
  for (int p = 0; p < 16; ++p) { accT[p] = 0.f; accN[p] = 0.f; }

#pragma unroll
  for (int t = 0; t < 3; ++t) {
#pragma unroll 2
    for (int a = 0; a < 11; ++a) {
      const float* row = &sPx[(t * 18 + r + a) * 28];
      float wv[26];
#pragma unroll
      for (int k = 0; k < 6; ++k) {
        const f32x4 q = *(const f32x4*)(row + 4 * k);
        wv[4 * k + 0] = q[0]; wv[4 * k + 1] = q[1];
        wv[4 * k + 2] = q[2]; wv[4 * k + 3] = q[3];
      }
      wv[24] = row[24]; wv[25] = row[25];

      const float* fr = fbase + (t * 11 + a) * 12;
      const f32x4 fq0 = *(const f32x4*)(fr);
      const f32x4 fq1 = *(const f32x4*)(fr + 4);
      const f32x4 fq2 = *(const f32x4*)(fr + 8);
      float fv[12];
#pragma unroll
      for (int k = 0; k < 4; ++k) { fv[k] = fq0[k]; fv[4+k] = fq1[k]; fv[8+k] = fq2[k]; }
      float fv2[12];
      if (t == 2) {
        const float* fr2 = fbase + (33 + a) * 12;
        const f32x4 g0 = *(const f32x4*)(fr2);
        const f32x4 g1 = *(const f32x4*)(fr2 + 4);
        const f32x4 g2 = *(const f32x4*)(fr2 + 8);
#pragma unroll
        for (int k = 0; k < 4; ++k) { fv2[k] = g0[k]; fv2[4+k] = g1[k]; fv2[8+k] = g2[k]; }
      }

#pragma unroll
      for (int b = 0; b < 11; ++b) {
        const float fT = fv[b];
#pragma unroll
        for (int p = 0; p < 16; ++p) accT[p] = fmaf(wv[b + p], fT, accT[p]);
        if (t == 2) {
          const float fN = fv2[b];
#pragma unroll
          for (int p = 0; p < 16; ++p) accN[p] = fmaf(wv[b + p], fN, accN[p]);
        }
      }
    }
  }

  float o0[16], o1[16];
#pragma unroll
  for (int p = 0; p < 16; ++p) {
    const float vT = fmaxf(accT[p], 0.f) * 0.5f;   // temp: relu(conv)/2
    const float vN = fmaxf(accN[p], 0.f);
    float s = vT + vN;
    s += __shfl_xor(s, 1);  s += __shfl_xor(s, 2);
    s += __shfl_xor(s, 4);  s += __shfl_xor(s, 8);
    const float inv = 1.f / (s + EPSF);
    o0[p] = vT * inv;
    o1[p] = vN * inv;
  }

  if (mode == 0) {
    // Direct fp8 pack into filtb (replaces pack_kernel). Valid crop:
    // rows i 11..372 -> filtb row i-6 (5..366); cols c 11..372 ->
    // xb=(c-11)>>3, byte jj=(c-11)&7. Byte off replicates old pack:
    // (xb>>3)*2048 + ((xb>>1)&1)*1024 + ((xb>>2)&1)*512 + o*16
    // + (xb&1)*8 + jj. Out-of-crop slots stay prep-zeroed.
    if (i >= 11 && i <= 372) {
      uchar_t* const rowbase = filtb + (size_t)(i - 6) * FILTB_ROW_B;
#pragma unroll
      for (int p = 0; p < 16; ++p) {
        const int c = j0 + p;
        if (c >= 11 && c <= 372) {
          const int cb = c - 11;
          const int xb = cb >> 3;
          const int off = (xb >> 3) * 2048 + ((xb >> 1) & 1) * 1024 +
                          ((xb >> 2) & 1) * 512 + (xb & 1) * 8 + (cb & 7);
          rowbase[off + chp * 16]        = (uchar_t)f32_to_e4m3(o0[p]);
          rowbase[off + (chp + 16) * 16] = (uchar_t)f32_to_e4m3(o1[p]);
        }
      }
    }
    // Direct x1 stores.
#pragma unroll
    for (int q = 0; q < 4; ++q) {
      f32x4 v0 = {o0[4*q], o0[4*q+1], o0[4*q+2], o0[4*q+3]};
      f32x4 v1 = {o1[4*q], o1[4*q+1], o1[4*q+2], o1[4*q+3]};
      *(f32x4*)(out_x1 + (size_t)chp * 147456 + i * 384 + j0 + 4 * q) = v0;
      *(f32x4*)(out_x1 + (size_t)(chp + 16) * 147456 + i * 384 + j0 + 4 * q) = v1;
    }
  } else {
    uint4_t u0, u1;
#pragma unroll
    for (int q = 0; q < 4; ++q) {
      u0[q] = f32_to_e4m3(o0[4*q]) | (f32_to_e4m3(o0[4*q+1]) << 8) |
              (f32_to_e4m3(o0[4*q+2]) << 16) | (f32_to_e4m3(o0[4*q+3]) << 24);
      u1[q] = f32_to_e4m3(o1[4*q]) | (f32_to_e4m3(o1[4*q+1]) << 8) |
              (f32_to_e4m3(o1[4*q+2]) << 16) | (f32_to_e4m3(o1[4*q+3]) << 24);
    }
    *(uint4_t*)(prevb + ((size_t)chp * 385 + i) * PREVB_STRIDE + j0) = u0;
    *(uint4_t*)(prevb + ((size_t)(chp + 16) * 385 + i) * PREVB_STRIDE + j0) = u1;
  }
}

// ---------------------------------------------------------------------------
// Stage 2: correlation via MX-scaled 32x32x64 fp8 MFMA (unit scales).
//   out[o,c,dy,dx] = sum_{y,x} filt[o][y-dy_a][x] * prev[c][y+6*dy_b][x+dx]
//   M=192=(dy_a 6)x(o 32); N=96: n = dyb*24+dx (dx 0..22, 23=pad);
//   K=(y, x): 6 kt64 steps of 64 per y.
// Block 1024 thr = 16 waves, producer-consumer (R20/R23 structure,
// UNCHANGED — corr is at its LDS-pipe plateau):
//   wv 0-11 = compute: 2 channel groups x 6 dy_a waves (pure-LDS K-loop,
//     0-deep loads, unroll 1); s_setprio(1) around the K-loop.
//   wv 12-15 = producers, one per SIMD: ALL staging.
// A: 8-slot LDS ring shared by both groups; producers write slot (y+6)&7.
// B: per-group double-buffered shifted-copy image. One barrier per y.
// Operand map (32x32x64 f8f6f4): m/n = lane&31, k = (lane>>5)*32 + j.
// C/D map: col = lane&31, row = (reg&3)+8*(reg>>2)+4*(lane>>5).
// ---------------------------------------------------------------------------
__global__ __launch_bounds__(1024, 4) void corr_kernel(
    const uchar_t* __restrict__ filtb, const uchar_t* __restrict__ prevb,
    float* __restrict__ x2)
{
  extern __shared__ uchar_t smem[];          // [A ring 98304][B 55296]

  const int tid = threadIdx.x;
  const int lane = tid & 63;
  const int wv = tid >> 6;               // 0..15
  const bool is_comp = (wv < 12);
  const int pw = wv - 12;                // producers 0..3 (neg for compute)
  const int cgu = is_comp ? ((wv >= 6) ? 1 : 0) : (pw >> 1);  // channel group
  const int w = is_comp ? (wv - 6 * ((wv >= 6) ? 1 : 0)) : 0; // dy_a
  const int kg = lane >> 5;              // k-group 0..1
  const int nn = lane & 31;              // n (or o) within tile

  const int chpair = blockIdx.x / NCHUNKS;     // 0..15
  const int chunk = blockIdx.x % NCHUNKS;      // 0..15; %8 == XCD
  const int ch = 2 * chpair + cgu;             // 0..31
  const int y0 = (chunk * YMAX) / NCHUNKS;     // balanced 22-23 y-steps
  const int y1 = ((chunk + 1) * YMAX) / NCHUNKS;

  uint_t* const sBg = (uint_t*)(smem + SA_BYTES) + cgu * (2 * (SB_ROW_B / 4));

  // Per-lane B window byte offsets within a y-row image (32B contiguous,
  // 8B-aligned): copy s = dx&7 is the row shifted by s bytes.
  int boffB[3];
#pragma unroll
  for (int nt = 0; nt < 3; ++nt) {
    const int n = nt * 32 + nn;          // 0..95
    const int dyb = n / 24;
    const int dxr = n - 24 * dyb;
    const int dx = (dxr < 23) ? dxr : 22;      // pad lane reads valid data
    const int s = dx & 7;
    boffB[nt] = dyb * SB_DYB_B + s * SB_COPY_B + (dx >> 3) * 8 + kg * 32;
  }

  // Producer B staging: 104 tasks per group from 2 waves (128 threads).
  const int tl = is_comp ? 0 : ((pw & 1) * 64 + lane);   // 0..127
  const bool b_act = (!is_comp) && (tl < 104);
  const int sdyb = b_act ? (tl / 26) : 0;
  const int sg = tl - 26 * (b_act ? (tl / 26) : 0);
  const uchar_t* srcbase = prevb + ((size_t)(ch * 385 + 6 * sdyb)) * PREVB_STRIDE;
  const int dstoff = sdyb * (SB_DYB_B / 4) + 4 * sg;     // word offset in buf

  // B: load row yy (24B window), expand to 8 byte-shifted copies in buf.
  auto stage_B = [&](int yy, int buf) {
    const uint_t* sw = (const uint_t*)(srcbase + (size_t)yy * PREVB_STRIDE) + 4 * sg;
    const uint4_t lo = *(const uint4_t*)(sw);
    const uint2_t hi = *(const uint2_t*)(sw + 4);
    const uint_t wd[6] = {lo.x, lo.y, lo.z, lo.w, hi.x, hi.y};
    uint_t* dst = sBg + buf * (SB_ROW_B / 4) + dstoff;
#pragma unroll
    for (int s = 0; s < 8; ++s) {
      const int off = s >> 2;
      const int b = (s & 3) * 8;
      uint4_t v;
      if (b == 0) {
        v = uint4_t{wd[off], wd[off + 1], wd[off + 2], wd[off + 3]};
      } else {
        v = uint4_t{(wd[off]     >> b) | (wd[off + 1] << (32 - b)),
                    (wd[off + 1] >> b) | (wd[off + 2] << (32 - b)),
                    (wd[off + 2] >> b) | (wd[off + 3] << (32 - b)),
                    (wd[off + 3] >> b) | (wd[off + 4] << (32 - b))};
      }
      *(uint4_t*)(dst + s * (SB_COPY_B / 4)) = v;
    }
  };

  // A: producers (ptid 0..255) copy one filtb row (48B each) into a slot.
  const int ptid = is_comp ? 0 : (pw * 64 + lane);
  auto stage_A = [&](int row, int slot) {
    const uchar_t* src = filtb + (size_t)row * FILTB_ROW_B + ptid * 48;
    uchar_t* dst = smem + (size_t)slot * FILTB_ROW_B + ptid * 48;
    const uint4_t v0 = *(const uint4_t*)(src);
    const uint4_t v1 = *(const uint4_t*)(src + 16);
    const uint4_t v2 = *(const uint4_t*)(src + 32);
    *(uint4_t*)(dst) = v0;
    *(uint4_t*)(dst + 16) = v1;
    *(uint4_t*)(dst + 32) = v2;
  };

  f32x16 acc[3];
#pragma unroll
  for (int nt = 0; nt < 3; ++nt)
#pragma unroll
    for (int r = 0; r < 16; ++r) acc[nt][r] = 0.f;

  // ---- Prologue (producers only) ----
  if (!is_comp) {
#pragma unroll
    for (int r6 = 0; r6 < 6; ++r6)
      stage_A(y0 + r6, (y0 + r6) & 7);
    if (b_act) stage_B(y0, 0);
  }
  __syncthreads();                       // A rows y0..y0+5 + B buf0 staged

  for (int y = y0; y < y1; ++y) {
    const int pb = (y - y0) & 1;         // B buffer consumers read this iter

    if (is_comp) {
      const char* sBrd = (const char*)sBg + pb * SB_ROW_B;
      const char* aRow = (const char*)smem +
          ((y + 5 - w) & 7) * FILTB_ROW_B + kg * 512 + nn * 16;

      // K-loop: 6 kt64 steps, pure LDS, minimal live registers.
      __builtin_amdgcn_s_setprio(1);
#pragma unroll 1
      for (int kt = 0; kt < 6; ++kt) {
        const char* ap = aRow + (kt << 11);
        const uint4_t a0 = *(const uint4_t*)(ap);          // h=0
        const uint4_t a1 = *(const uint4_t*)(ap + 1024);   // h=1
        const int8v Af = {(int)a0.x, (int)a0.y, (int)a0.z, (int)a0.w,
                          (int)a1.x, (int)a1.y, (int)a1.z, (int)a1.w};
#pragma unroll
        for (int nt = 0; nt < 3; ++nt) {
          const char* bp = sBrd + boffB[nt] + (kt << 6);
          const uint2_t b0 = *(const uint2_t*)(bp);
          const uint2_t b1 = *(const uint2_t*)(bp + 8);
          const uint2_t b2 = *(const uint2_t*)(bp + 16);
          const uint2_t b3 = *(const uint2_t*)(bp + 24);
          const int8v Bf = {(int)b0.x, (int)b0.y, (int)b1.x, (int)b1.y,
                            (int)b2.x, (int)b2.y, (int)b3.x, (int)b3.y};
          acc[nt] = __builtin_amdgcn_mfma_scale_f32_32x32x64_f8f6f4(
              Af, Bf, acc[nt], 0, 0,                // fmtA=FP8, fmtB=FP8
              0, 0x7F7F7F7F, 0, 0x7F7F7F7F);        // unit E8M0 scales
        }
      }
      __builtin_amdgcn_s_setprio(0);
    } else {
      // Producers: stage B row y+1 into buf pb^1 (consumers read pb), and
      // A row y+6 into ring slot (y+6)&7 (consumers read slots y..y+5).
      if (b_act && y + 1 < y1) stage_B(y + 1, pb ^ 1);
      if (y + 6 <= y1 + 4) stage_A(y + 6, (y + 6) & 7);
    }

    __syncthreads();                     // A row y+6 + B buf y+1 visible
  }

  // Epilogue: scale partials, atomically accumulate into x2[o][c][dy][dx].
  if (is_comp) {
#pragma unroll
    for (int nt = 0; nt < 3; ++nt) {
      const int n = nt * 32 + nn;
      const int dyb = n / 24;
      const int dxr = n - 24 * dyb;
      if (dxr < 23) {
        const int dy = w + 6 * dyb;
        if (dy <= 22) {
#pragma unroll
          for (int r = 0; r < 16; ++r) {
            const int o = (r & 3) + 8 * (r >> 2) + 4 * kg;   // C/D row
            atomicAdd(&x2[((o * 32 + ch) * 23 + dy) * 23 + dxr],
                      acc[nt][r] * INV_AREA);
          }
        }
      }
    }
  }
}

// ---------------------------------------------------------------------------
extern "C" void kernel_launch(void* const* d_in, const int* in_sizes, int n_in,
                              void* d_out, int out_size, void* d_ws, size_t ws_size,
                              hipStream_t stream)
{
  const float* x     = (const float*)d_in[0];   // [3][394][394]
  const float* xprev = (const float*)d_in[1];
  const float* ft    = (const float*)d_in[2];   // [16][3][11][11]
  const float* fn    = (const float*)d_in[3];   // [16][1][11][11]
  float* out = (float*)d_out;

  uchar_t* filtb = (uchar_t*)d_ws;
  uchar_t* prevb = filtb + FILTB_BYTES;
  float* fT2 = (float*)(prevb + PREVB_BYTES);

  static bool attr_set = false;
  if (!attr_set) {
    (void)hipFuncSetAttribute((const void*)corr_kernel,
        hipFuncAttributeMaxDynamicSharedMemorySize, SMEM_TOTAL);
    attr_set = true;
  }

  // 3 dispatches: prep (fused zeros + filter pack) -> feat (feats + x1 +
  // direct filtb/prevb pack) -> corr.
  prep_kernel<<<dim3((PREP_WORK + 255) / 256), 256, 0, stream>>>(
      ft, fn, fT2, (uchar_t*)d_ws, out + X1_N);
  feat_kernel<<<dim3(24, 48, 2), 128, 0, stream>>>(
      x, xprev, fT2, out, prevb, filtb);
  corr_kernel<<<dim3(16 * NCHUNKS), 1024, SMEM_TOTAL, stream>>>(
      filtb, prevb, out + X1_N);
}